// Round 1
// baseline (530.907 us; speedup 1.0000x reference)
//
#include <hip/hip_runtime.h>

// ---------- types ----------
typedef __attribute__((ext_vector_type(8))) __bf16 bf16x8;   // MFMA A/B frag (4 VGPR)
typedef __attribute__((ext_vector_type(4))) float f32x4;     // MFMA C/D frag

// fp32 -> bf16 (RNE, no NaN inputs expected)
__device__ __forceinline__ ushort f2bf(float x) {
    unsigned u = __builtin_bit_cast(unsigned, x);
    unsigned r = u + 0x7fffu + ((u >> 16) & 1u);
    return (ushort)(r >> 16);
}
__device__ __forceinline__ float bf2f(ushort u) {
    unsigned v = ((unsigned)u) << 16;
    return __builtin_bit_cast(float, v);
}

// async global->LDS, 16B per lane. LDS dest = wave-uniform base + lane*16.
__device__ __forceinline__ void gload16(const void* g, void* l) {
    __builtin_amdgcn_global_load_lds(
        (const __attribute__((address_space(1))) void*)g,
        (__attribute__((address_space(3))) void*)l,
        16, 0, 0);
}

// ---------- conversion kernels ----------
__global__ __launch_bounds__(256) void cvt_f32_bf16(const float* __restrict__ in,
                                                    ushort* __restrict__ out, int n4) {
    int i = blockIdx.x * 256 + threadIdx.x;
    int stride = gridDim.x * 256;
    for (; i < n4; i += stride) {
        float4 v = ((const float4*)in)[i];
        ushort4 o;
        o.x = f2bf(v.x); o.y = f2bf(v.y); o.z = f2bf(v.z); o.w = f2bf(v.w);
        ((ushort4*)out)[i] = o;
    }
}

// query (4096x1024 f32) -> cat buffer cols 0..1023 (row stride 2048, bf16)
__global__ __launch_bounds__(256) void cvt_query_cat(const float* __restrict__ in,
                                                     ushort* __restrict__ cat) {
    const int r = blockIdx.x, t = threadIdx.x;
    float4 v = ((const float4*)(in + (size_t)r * 1024))[t];
    ushort4 o;
    o.x = f2bf(v.x); o.y = f2bf(v.y); o.z = f2bf(v.z); o.w = f2bf(v.w);
    ((ushort4*)(cat + (size_t)r * 2048))[t] = o;
}

// ---------- GEMM: C = A(MxK,bf16) @ W(NxK,bf16)^T + bias ----------
// 128x128x64 tiles, 4 waves (2x2), acc 4x4 of 16x16 frags per wave.
// EPI 0: bf16 out, (acc+bias)*scale          (ld0 = N)
// EPI 1: bf16 out TRANSPOSED out[col*ld0+row] (ld0 = Mrows)
// EPI 2: f32 out (ld0) + bf16 out into o_bf with row stride 2048
// EPI 3: silu(acc+bias) -> bf16 out (ld0)
template<int EPI>
__global__ __launch_bounds__(256) void gemm_bt(
    const ushort* __restrict__ A, int lda,
    const ushort* __restrict__ Bw, int ldb,
    const float* __restrict__ bias,
    ushort* __restrict__ o_bf, int ld0,
    float* __restrict__ o_f32,
    int K, float scale)
{
    __shared__ __align__(1024) char smem[32768];
    char* As = smem;
    char* Bs = smem + 16384;
    const int t = threadIdx.x, w = t >> 6, l = t & 63, g = l >> 4, c = l & 15;
    const int wr = w >> 1, wc = w & 1;
    const long m0 = (long)blockIdx.y * 128, n0 = (long)blockIdx.x * 128;
    const size_t ldaB = (size_t)lda * 2, ldbB = (size_t)ldb * 2;
    const int swz = (c & 7) << 4;

    f32x4 acc[4][4];
#pragma unroll
    for (int i = 0; i < 4; ++i)
#pragma unroll
        for (int j = 0; j < 4; ++j) acc[i][j] = (f32x4)0.0f;

    const int nkt = K >> 6;
    for (int kt = 0; kt < nkt; ++kt) {
        __syncthreads();
        const char* Ab = (const char*)A + (size_t)kt * 128;
        const char* Bb = (const char*)Bw + (size_t)kt * 128;
#pragma unroll
        for (int i = 0; i < 4; ++i) {
            int seg = i * 4 + w;
            int o = seg * 1024 + l * 16;
            int row = o >> 7, cb = o & 127;
            gload16(Ab + (size_t)(m0 + row) * ldaB + (cb ^ ((row & 7) << 4)), As + seg * 1024);
            gload16(Bb + (size_t)(n0 + row) * ldbB + (cb ^ ((row & 7) << 4)), Bs + seg * 1024);
        }
        __syncthreads();
        bf16x8 af[2][4], bfr[2][4];
#pragma unroll
        for (int kf = 0; kf < 2; ++kf) {
            int cbk = (kf * 64 + g * 16) ^ swz;
#pragma unroll
            for (int i = 0; i < 4; ++i) {
                af[kf][i]  = *(const bf16x8*)(As + (wr * 64 + i * 16 + c) * 128 + cbk);
                bfr[kf][i] = *(const bf16x8*)(Bs + (wc * 64 + i * 16 + c) * 128 + cbk);
            }
        }
#pragma unroll
        for (int kf = 0; kf < 2; ++kf)
#pragma unroll
            for (int i = 0; i < 4; ++i)
#pragma unroll
                for (int j = 0; j < 4; ++j)
                    acc[i][j] = __builtin_amdgcn_mfma_f32_16x16x32_bf16(
                        af[kf][i], bfr[kf][j], acc[i][j], 0, 0, 0);
    }

    // epilogue: C/D layout col = l&15, row = (l>>4)*4 + jj  [verified m89/m91]
#pragma unroll
    for (int i = 0; i < 4; ++i)
#pragma unroll
        for (int j = 0; j < 4; ++j) {
            const long col = n0 + wc * 64 + j * 16 + c;
            const float bs = bias[col];
            const long rowb = m0 + wr * 64 + i * 16 + g * 4;
            if (EPI == 1) {
                ushort4 o;
                o.x = f2bf(acc[i][j][0] + bs);
                o.y = f2bf(acc[i][j][1] + bs);
                o.z = f2bf(acc[i][j][2] + bs);
                o.w = f2bf(acc[i][j][3] + bs);
                *(ushort4*)(o_bf + col * (long)ld0 + rowb) = o;
            } else {
#pragma unroll
                for (int jj = 0; jj < 4; ++jj) {
                    const long row = rowb + jj;
                    const float v = acc[i][j][jj] + bs;
                    if (EPI == 0) {
                        o_bf[row * (long)ld0 + col] = f2bf(v * scale);
                    } else if (EPI == 2) {
                        o_f32[row * (long)ld0 + col] = v;
                        o_bf[row * 2048 + col] = f2bf(v);
                    } else { // EPI == 3 : silu
                        const float sv = v / (1.0f + __expf(-v));
                        o_bf[row * (long)ld0 + col] = f2bf(sv);
                    }
                }
            }
        }
}

// ---------- flash attention ----------
// grid (S/64, H, B), 256 threads = 4 waves; wave owns 16 q-rows.
// qp: (B*S)x1024 bf16, PRE-SCALED by Dh^-0.5*log2(e); kp: (B*M)x1024 bf16;
// vT: 1024x(B*M) bf16 (transposed V projection); out: (B*S)x1024 bf16.
__global__ __launch_bounds__(256) void attn_fwd(
    const ushort* __restrict__ qp, const ushort* __restrict__ kp,
    const ushort* __restrict__ vT, ushort* __restrict__ out)
{
    __shared__ __align__(1024) char smem[49152];
    char* Ks = smem;              // [128 m][128B] swizzled
    char* Vs = smem + 16384;      // [64 d][256B] swizzled
    char* Ps = smem + 32768;      // 4 x [16 s][256B] per-wave, swizzled
    const int t = threadIdx.x, w = t >> 6, l = t & 63, g = l >> 4, c = l & 15;
    const int b = blockIdx.z, h = blockIdx.y;
    const int s0 = blockIdx.x * 64 + w * 16;
    const int swz = (c & 7) << 4;

    // Q A-frags: row = s0+c, k = kf*32 + g*8 .. +7
    const size_t qbase = ((size_t)b * 2048 + s0 + c) * 1024 + h * 64 + g * 8;
    bf16x8 qf0 = *(const bf16x8*)(qp + qbase);
    bf16x8 qf1 = *(const bf16x8*)(qp + qbase + 32);

    f32x4 oacc[4];
    float mrow[4], lrow[4];
#pragma unroll
    for (int d = 0; d < 4; ++d) oacc[d] = (f32x4)0.0f;
#pragma unroll
    for (int j = 0; j < 4; ++j) { mrow[j] = -1e30f; lrow[j] = 0.0f; }

    const char* kpB = (const char*)kp + (size_t)b * 4096 * 2048 + h * 128;
    const char* vTB = (const char*)vT + (size_t)h * 64 * 16384 + (size_t)b * 4096 * 2;
    char* Pw = Ps + w * 4096;

    for (int mt = 0; mt < 4096; mt += 128) {
        __syncthreads();
#pragma unroll
        for (int i = 0; i < 4; ++i) {
            int seg = i * 4 + w;
            {   // K tile: [128 rows][128B]
                int o = seg * 1024 + l * 16, row = o >> 7, cb = o & 127;
                gload16(kpB + (size_t)(mt + row) * 2048 + (cb ^ ((row & 7) << 4)), Ks + seg * 1024);
            }
            {   // V^T tile: [64 rows][256B]
                int o = seg * 1024 + l * 16, row = o >> 8, cb = o & 255;
                gload16(vTB + (size_t)row * 16384 + (size_t)mt * 2 + (cb ^ ((row & 7) << 4)), Vs + seg * 1024);
            }
        }
        __syncthreads();

        // S = Q K^T (pre-scaled, base-2 domain)
        f32x4 sacc[8];
#pragma unroll
        for (int mf = 0; mf < 8; ++mf) sacc[mf] = (f32x4)0.0f;
#pragma unroll
        for (int kf = 0; kf < 2; ++kf) {
            const int cbk = (kf * 64 + g * 16) ^ swz;
            const bf16x8 q = kf ? qf1 : qf0;
#pragma unroll
            for (int mf = 0; mf < 8; ++mf) {
                bf16x8 kb = *(const bf16x8*)(Ks + (mf * 16 + c) * 128 + cbk);
                sacc[mf] = __builtin_amdgcn_mfma_f32_16x16x32_bf16(q, kb, sacc[mf], 0, 0, 0);
            }
        }

        // online softmax (row r = g*4+j spread over 16-lane group, 8 m-frags)
        float nm[4], al[4];
#pragma unroll
        for (int j = 0; j < 4; ++j) {
            float tm = sacc[0][j];
#pragma unroll
            for (int mf = 1; mf < 8; ++mf) tm = fmaxf(tm, sacc[mf][j]);
            for (int msk = 1; msk < 16; msk <<= 1) tm = fmaxf(tm, __shfl_xor(tm, msk));
            nm[j] = fmaxf(mrow[j], tm);
            al[j] = exp2f(mrow[j] - nm[j]);
            mrow[j] = nm[j];
        }
        float rs[4] = {0.f, 0.f, 0.f, 0.f};
#pragma unroll
        for (int mf = 0; mf < 8; ++mf) {
            const int colb = (mf * 16 + c) * 2;
#pragma unroll
            for (int j = 0; j < 4; ++j) {
                float p = exp2f(sacc[mf][j] - nm[j]);
                rs[j] += p;
                const int rowp = g * 4 + j;
                *(ushort*)(Pw + rowp * 256 + (colb ^ ((rowp & 7) << 4))) = f2bf(p);
            }
        }
#pragma unroll
        for (int j = 0; j < 4; ++j) {
            float s = rs[j];
            for (int msk = 1; msk < 16; msk <<= 1) s += __shfl_xor(s, msk);
            lrow[j] = lrow[j] * al[j] + s;
#pragma unroll
            for (int df = 0; df < 4; ++df) oacc[df][j] *= al[j];
        }

        // O += P V  (A = P from own-wave LDS, B = V via V^T tile)
#pragma unroll
        for (int km = 0; km < 4; ++km) {
            const int cbm = (km * 64 + g * 16) ^ swz;
            bf16x8 pa = *(const bf16x8*)(Pw + c * 256 + cbm);
#pragma unroll
            for (int df = 0; df < 4; ++df) {
                bf16x8 vb = *(const bf16x8*)(Vs + (df * 16 + c) * 256 + cbm);
                oacc[df] = __builtin_amdgcn_mfma_f32_16x16x32_bf16(pa, vb, oacc[df], 0, 0, 0);
            }
        }
    }

    const size_t obase = ((size_t)b * 2048 + s0 + g * 4) * 1024 + h * 64 + c;
#pragma unroll
    for (int df = 0; df < 4; ++df)
#pragma unroll
        for (int j = 0; j < 4; ++j)
            out[obase + (size_t)j * 1024 + df * 16] = f2bf(oacc[df][j] / lrow[j]);
}

// ---------- gate + residual ----------
// per row: gate = sigmoid(dot(g_silu, Wg2) + bg2); out = query + gate*retr
__global__ __launch_bounds__(256) void gate_out_k(
    const ushort* __restrict__ gs, const float* __restrict__ Wg2,
    const float* __restrict__ bg2, const float* __restrict__ query,
    const float* __restrict__ retr, float* __restrict__ out)
{
    const int r = blockIdx.x, t = threadIdx.x, w = t >> 6, l = t & 63;
    ushort4 gv = ((const ushort4*)(gs + (size_t)r * 1024))[t];
    float4 wv = ((const float4*)Wg2)[t];
    float p = bf2f(gv.x) * wv.x + bf2f(gv.y) * wv.y + bf2f(gv.z) * wv.z + bf2f(gv.w) * wv.w;
    for (int m = 1; m < 64; m <<= 1) p += __shfl_xor(p, m);
    __shared__ float red[4];
    if (l == 0) red[w] = p;
    __syncthreads();
    const float dot = red[0] + red[1] + red[2] + red[3] + bg2[0];
    const float gate = 1.0f / (1.0f + __expf(-dot));
    float4 q = ((const float4*)(query + (size_t)r * 1024))[t];
    float4 rt = ((const float4*)(retr + (size_t)r * 1024))[t];
    float4 o;
    o.x = q.x + gate * rt.x; o.y = q.y + gate * rt.y;
    o.z = q.z + gate * rt.z; o.w = q.w + gate * rt.w;
    ((float4*)(out + (size_t)r * 1024))[t] = o;
}

// ---------- launcher ----------
extern "C" void kernel_launch(void* const* d_in, const int* in_sizes, int n_in,
                              void* d_out, int out_size, void* d_ws, size_t ws_size,
                              hipStream_t stream) {
    const float* query = (const float*)d_in[0];   // 2x2048x1024
    const float* mkeys = (const float*)d_in[1];   // 2x4096x768
    const float* mvals = (const float*)d_in[2];   // 2x4096x768
    const float* Wq  = (const float*)d_in[3];
    const float* bq  = (const float*)d_in[4];
    const float* Wk  = (const float*)d_in[5];
    const float* bk  = (const float*)d_in[6];
    const float* Wv  = (const float*)d_in[7];
    const float* bv  = (const float*)d_in[8];
    const float* Wo  = (const float*)d_in[9];
    const float* bo  = (const float*)d_in[10];
    const float* Wg1 = (const float*)d_in[11];
    const float* bg1 = (const float*)d_in[12];
    const float* Wg2 = (const float*)d_in[13];
    const float* bg2 = (const float*)d_in[14];
    float* outF = (float*)d_out;

    char* ws = (char*)d_ws;
    size_t off = 0;
    auto take = [&](size_t bytes) { char* p = ws + off; off += (bytes + 255) & ~(size_t)255; return p; };
    ushort* cat    = (ushort*)take((size_t)4096 * 2048 * 2); // [query_bf | retro_bf]
    ushort* mkbf   = (ushort*)take((size_t)8192 * 768 * 2);
    ushort* mvbf   = (ushort*)take((size_t)8192 * 768 * 2);
    ushort* wqbf   = (ushort*)take((size_t)1024 * 1024 * 2);
    ushort* wkbf   = (ushort*)take((size_t)1024 * 768 * 2);
    ushort* wvbf   = (ushort*)take((size_t)1024 * 768 * 2);
    ushort* wobf   = (ushort*)take((size_t)1024 * 1024 * 2);
    ushort* wg1bf  = (ushort*)take((size_t)1024 * 2048 * 2);
    ushort* qproj  = (ushort*)take((size_t)4096 * 1024 * 2);
    ushort* kproj  = (ushort*)take((size_t)8192 * 1024 * 2);
    ushort* vprojT = (ushort*)take((size_t)1024 * 8192 * 2);
    ushort* attno  = (ushort*)take((size_t)4096 * 1024 * 2);
    float*  retro  = (float*)take((size_t)4096 * 1024 * 4);
    ushort* gsilu  = (ushort*)take((size_t)4096 * 1024 * 2);

    // conversions
    cvt_query_cat<<<4096, 256, 0, stream>>>(query, cat);
    cvt_f32_bf16<<<2048, 256, 0, stream>>>(mkeys, mkbf, 8192 * 768 / 4);
    cvt_f32_bf16<<<2048, 256, 0, stream>>>(mvals, mvbf, 8192 * 768 / 4);
    cvt_f32_bf16<<<512, 256, 0, stream>>>(Wq, wqbf, 1024 * 1024 / 4);
    cvt_f32_bf16<<<512, 256, 0, stream>>>(Wk, wkbf, 1024 * 768 / 4);
    cvt_f32_bf16<<<512, 256, 0, stream>>>(Wv, wvbf, 1024 * 768 / 4);
    cvt_f32_bf16<<<512, 256, 0, stream>>>(Wo, wobf, 1024 * 1024 / 4);
    cvt_f32_bf16<<<512, 256, 0, stream>>>(Wg1, wg1bf, 1024 * 2048 / 4);

    // Q = (query Wq^T + bq) * Dh^-0.5 * log2(e)   [base-2 softmax domain]
    const float qscale = 0.125f * 1.44269504088896340736f;
    gemm_bt<0><<<dim3(8, 32), 256, 0, stream>>>(cat, 2048, wqbf, 1024, bq, qproj, 1024, nullptr, 1024, qscale);
    // K = mk Wk^T + bk
    gemm_bt<0><<<dim3(8, 64), 256, 0, stream>>>(mkbf, 768, wkbf, 768, bk, kproj, 1024, nullptr, 768, 1.0f);
    // V^T = (mv Wv^T + bv)^T
    gemm_bt<1><<<dim3(8, 64), 256, 0, stream>>>(mvbf, 768, wvbf, 768, bv, vprojT, 8192, nullptr, 768, 1.0f);
    // attention
    attn_fwd<<<dim3(32, 16, 2), 256, 0, stream>>>(qproj, kproj, vprojT, attno);
    // retr_o = attn_out Wo^T + bo  -> f32 (residual) + bf16 into cat cols 1024..2047
    gemm_bt<2><<<dim3(8, 32), 256, 0, stream>>>(attno, 1024, wobf, 1024, bo, cat + 1024, 1024, retro, 1024, 1.0f);
    // g = silu([query; retr_o] Wg1^T + bg1)
    gemm_bt<3><<<dim3(8, 32), 256, 0, stream>>>(cat, 2048, wg1bf, 2048, bg1, gsilu, 1024, nullptr, 2048, 1.0f);
    // gate + residual
    gate_out_k<<<4096, 256, 0, stream>>>(gsilu, Wg2, bg2, query, retro, outF);
}

// Round 2
// 451.644 us; speedup vs baseline: 1.1755x; 1.1755x over previous
//
#include <hip/hip_runtime.h>

// ---------- types ----------
typedef __attribute__((ext_vector_type(8))) __bf16 bf16x8;   // MFMA A/B frag (4 VGPR)
typedef __attribute__((ext_vector_type(4))) float f32x4;     // MFMA C/D frag

// fp32 -> bf16 (RNE, no NaN inputs expected)
__device__ __forceinline__ ushort f2bf(float x) {
    unsigned u = __builtin_bit_cast(unsigned, x);
    unsigned r = u + 0x7fffu + ((u >> 16) & 1u);
    return (ushort)(r >> 16);
}
__device__ __forceinline__ float bf2f(ushort u) {
    unsigned v = ((unsigned)u) << 16;
    return __builtin_bit_cast(float, v);
}

// packed f32x2 -> bf16x2 (T12)
__device__ __forceinline__ unsigned cvtpk(float lo, float hi) {
    unsigned r;
    asm("v_cvt_pk_bf16_f32 %0, %1, %2" : "=v"(r) : "v"(lo), "v"(hi));
    return r;
}

// async global->LDS, 16B per lane. LDS dest = wave-uniform base + lane*16.
__device__ __forceinline__ void gload16(const void* g, void* l) {
    __builtin_amdgcn_global_load_lds(
        (const __attribute__((address_space(1))) void*)g,
        (__attribute__((address_space(3))) void*)l,
        16, 0, 0);
}

// ---------- conversion kernels ----------
__global__ __launch_bounds__(256) void cvt_f32_bf16(const float* __restrict__ in,
                                                    ushort* __restrict__ out, int n4) {
    int i = blockIdx.x * 256 + threadIdx.x;
    int stride = gridDim.x * 256;
    for (; i < n4; i += stride) {
        float4 v = ((const float4*)in)[i];
        ushort4 o;
        o.x = f2bf(v.x); o.y = f2bf(v.y); o.z = f2bf(v.z); o.w = f2bf(v.w);
        ((ushort4*)out)[i] = o;
    }
}

// query (4096x1024 f32) -> cat buffer cols 0..1023 (row stride 2048, bf16)
__global__ __launch_bounds__(256) void cvt_query_cat(const float* __restrict__ in,
                                                     ushort* __restrict__ cat) {
    const int r = blockIdx.x, t = threadIdx.x;
    float4 v = ((const float4*)(in + (size_t)r * 1024))[t];
    ushort4 o;
    o.x = f2bf(v.x); o.y = f2bf(v.y); o.z = f2bf(v.z); o.w = f2bf(v.w);
    ((ushort4*)(cat + (size_t)r * 2048))[t] = o;
}

// ---------- GEMM: C = A(MxK,bf16) @ W(NxK,bf16)^T + bias ----------
// 128x128x64 tiles, 4 waves (2x2), acc 4x4 of 16x16 frags per wave.
// EPI 0: bf16 out, (acc+bias)*scale          (ld0 = N)
// EPI 1: bf16 out TRANSPOSED out[col*ld0+row] (ld0 = Mrows)
// EPI 2: f32 out (ld0) + bf16 out into o_bf with row stride 2048
// EPI 3: silu(acc+bias) -> bf16 out (ld0)
template<int EPI>
__global__ __launch_bounds__(256) void gemm_bt(
    const ushort* __restrict__ A, int lda,
    const ushort* __restrict__ Bw, int ldb,
    const float* __restrict__ bias,
    ushort* __restrict__ o_bf, int ld0,
    float* __restrict__ o_f32,
    int K, float scale)
{
    __shared__ __align__(1024) char smem[32768];
    char* As = smem;
    char* Bs = smem + 16384;
    const int t = threadIdx.x, w = t >> 6, l = t & 63, g = l >> 4, c = l & 15;
    const int wr = w >> 1, wc = w & 1;
    const long m0 = (long)blockIdx.y * 128, n0 = (long)blockIdx.x * 128;
    const size_t ldaB = (size_t)lda * 2, ldbB = (size_t)ldb * 2;
    const int swz = (c & 7) << 4;

    f32x4 acc[4][4];
#pragma unroll
    for (int i = 0; i < 4; ++i)
#pragma unroll
        for (int j = 0; j < 4; ++j) acc[i][j] = (f32x4)0.0f;

    const int nkt = K >> 6;
    for (int kt = 0; kt < nkt; ++kt) {
        __syncthreads();
        const char* Ab = (const char*)A + (size_t)kt * 128;
        const char* Bb = (const char*)Bw + (size_t)kt * 128;
#pragma unroll
        for (int i = 0; i < 4; ++i) {
            int seg = i * 4 + w;
            int o = seg * 1024 + l * 16;
            int row = o >> 7, cb = o & 127;
            gload16(Ab + (size_t)(m0 + row) * ldaB + (cb ^ ((row & 7) << 4)), As + seg * 1024);
            gload16(Bb + (size_t)(n0 + row) * ldbB + (cb ^ ((row & 7) << 4)), Bs + seg * 1024);
        }
        __syncthreads();
        bf16x8 af[2][4], bfr[2][4];
#pragma unroll
        for (int kf = 0; kf < 2; ++kf) {
            int cbk = (kf * 64 + g * 16) ^ swz;
#pragma unroll
            for (int i = 0; i < 4; ++i) {
                af[kf][i]  = *(const bf16x8*)(As + (wr * 64 + i * 16 + c) * 128 + cbk);
                bfr[kf][i] = *(const bf16x8*)(Bs + (wc * 64 + i * 16 + c) * 128 + cbk);
            }
        }
#pragma unroll
        for (int kf = 0; kf < 2; ++kf)
#pragma unroll
            for (int i = 0; i < 4; ++i)
#pragma unroll
                for (int j = 0; j < 4; ++j)
                    acc[i][j] = __builtin_amdgcn_mfma_f32_16x16x32_bf16(
                        af[kf][i], bfr[kf][j], acc[i][j], 0, 0, 0);
    }

    // epilogue: C/D layout col = l&15, row = (l>>4)*4 + jj  [verified m89/m91]
#pragma unroll
    for (int i = 0; i < 4; ++i)
#pragma unroll
        for (int j = 0; j < 4; ++j) {
            const long col = n0 + wc * 64 + j * 16 + c;
            const float bs = bias[col];
            const long rowb = m0 + wr * 64 + i * 16 + g * 4;
            if (EPI == 1) {
                ushort4 o;
                o.x = f2bf(acc[i][j][0] + bs);
                o.y = f2bf(acc[i][j][1] + bs);
                o.z = f2bf(acc[i][j][2] + bs);
                o.w = f2bf(acc[i][j][3] + bs);
                *(ushort4*)(o_bf + col * (long)ld0 + rowb) = o;
            } else {
#pragma unroll
                for (int jj = 0; jj < 4; ++jj) {
                    const long row = rowb + jj;
                    const float v = acc[i][j][jj] + bs;
                    if (EPI == 0) {
                        o_bf[row * (long)ld0 + col] = f2bf(v * scale);
                    } else if (EPI == 2) {
                        o_f32[row * (long)ld0 + col] = v;
                        o_bf[row * 2048 + col] = f2bf(v);
                    } else { // EPI == 3 : silu
                        const float sv = v / (1.0f + __expf(-v));
                        o_bf[row * (long)ld0 + col] = f2bf(sv);
                    }
                }
            }
        }
}

// ---------- flash attention (swapped-QK^T, in-register softmax) ----------
// grid (S/64, H, B), 256 threads = 4 waves; wave owns 16 q-rows.
// qp: (B*S)x1024 bf16, PRE-SCALED by Dh^-0.5*log2(e); kp: (B*M)x1024 bf16;
// vT: 1024x(B*M) bf16 (transposed V projection); out: (B*S)x1024 bf16.
//
// S^T trick: sacc[mf] = mfma(K_frag, Q_frag) -> C col (l&15)=c is the q-row,
// C row (g*4+j) is the k-row. Each lane owns P[q=s0+c][k=mf*16+g*4+j] (32 vals)
// -> lane-local max/sum + 2 shfl_xor rounds (16,32); pack via v_cvt_pk_bf16_f32
// and ds_write_b64 into a per-wave half-P buffer (128B rows, XOR-swizzled).
__global__ __launch_bounds__(256, 4) void attn_fwd(
    const ushort* __restrict__ qp, const ushort* __restrict__ kp,
    const ushort* __restrict__ vT, ushort* __restrict__ out)
{
    __shared__ __align__(1024) char smem[40960];
    char* Ks = smem;              // [128 m][128B] swizzled
    char* Vs = smem + 16384;      // [64 d][256B] swizzled
    char* Ps = smem + 32768;      // 4 x [16 q][128B] per-wave half-P, swizzled
    const int t = threadIdx.x, w = t >> 6, l = t & 63, g = l >> 4, c = l & 15;
    const int b = blockIdx.z, h = blockIdx.y;
    const int s0 = blockIdx.x * 64 + w * 16;
    const int swz = (c & 7) << 4;

    // Q frag (B-operand role; layout identical to A): row = s0+c, k = kf*32+g*8..+7
    const size_t qbase = ((size_t)b * 2048 + s0 + c) * 1024 + h * 64 + g * 8;
    const bf16x8 qf0 = *(const bf16x8*)(qp + qbase);
    const bf16x8 qf1 = *(const bf16x8*)(qp + qbase + 32);

    f32x4 oacc[4];
#pragma unroll
    for (int d = 0; d < 4; ++d) oacc[d] = (f32x4)0.0f;
    float mrow = -1e30f, lrow = 0.0f;   // stats for q-row = s0 + c (dup over g)

    const char* kpB = (const char*)kp + (size_t)b * 4096 * 2048 + h * 128;
    const char* vTB = (const char*)vT + (size_t)h * 64 * 16384 + (size_t)b * 4096 * 2;
    char* Pw = Ps + w * 2048;

    for (int mt = 0; mt < 4096; mt += 128) {
        __syncthreads();
#pragma unroll
        for (int i = 0; i < 4; ++i) {
            int seg = i * 4 + w;
            int o = seg * 1024 + l * 16;
            {   // K tile: [128 rows][128B]
                int row = o >> 7, cb = o & 127;
                gload16(kpB + (size_t)(mt + row) * 2048 + (cb ^ ((row & 7) << 4)), Ks + seg * 1024);
            }
            {   // V^T tile: [64 rows][256B]
                int row = o >> 8, cb = o & 255;
                gload16(vTB + (size_t)row * 16384 + (size_t)mt * 2 + (cb ^ ((row & 7) << 4)), Vs + seg * 1024);
            }
        }
        __syncthreads();

        // S^T = K Q^T : lane (c,g) gets S[q=s0+c][k = mf*16+g*4+j]
        f32x4 sacc[8];
#pragma unroll
        for (int mf = 0; mf < 8; ++mf) sacc[mf] = (f32x4)0.0f;
#pragma unroll
        for (int kf = 0; kf < 2; ++kf) {
            const int cbk = (kf * 64 + g * 16) ^ swz;
            const bf16x8 q = kf ? qf1 : qf0;
#pragma unroll
            for (int mf = 0; mf < 8; ++mf) {
                bf16x8 kb = *(const bf16x8*)(Ks + (mf * 16 + c) * 128 + cbk);
                sacc[mf] = __builtin_amdgcn_mfma_f32_16x16x32_bf16(kb, q, sacc[mf], 0, 0, 0);
            }
        }

        // lane-local max tree over 32 values + cross-g reduce (2 rounds)
        float tm;
        {
            float a0 = fmaxf(fmaxf(sacc[0][0], sacc[0][1]), fmaxf(sacc[0][2], sacc[0][3]));
            float a1 = fmaxf(fmaxf(sacc[1][0], sacc[1][1]), fmaxf(sacc[1][2], sacc[1][3]));
            float a2 = fmaxf(fmaxf(sacc[2][0], sacc[2][1]), fmaxf(sacc[2][2], sacc[2][3]));
            float a3 = fmaxf(fmaxf(sacc[3][0], sacc[3][1]), fmaxf(sacc[3][2], sacc[3][3]));
            float a4 = fmaxf(fmaxf(sacc[4][0], sacc[4][1]), fmaxf(sacc[4][2], sacc[4][3]));
            float a5 = fmaxf(fmaxf(sacc[5][0], sacc[5][1]), fmaxf(sacc[5][2], sacc[5][3]));
            float a6 = fmaxf(fmaxf(sacc[6][0], sacc[6][1]), fmaxf(sacc[6][2], sacc[6][3]));
            float a7 = fmaxf(fmaxf(sacc[7][0], sacc[7][1]), fmaxf(sacc[7][2], sacc[7][3]));
            tm = fmaxf(fmaxf(fmaxf(a0, a1), fmaxf(a2, a3)), fmaxf(fmaxf(a4, a5), fmaxf(a6, a7)));
        }
        tm = fmaxf(tm, __shfl_xor(tm, 16));
        tm = fmaxf(tm, __shfl_xor(tm, 32));

        // T13 defer-max: only rescale when the tile max outgrows m by >8 (2^8 bound)
        if (!__all(tm <= mrow + 8.0f)) {
            const float nm = fmaxf(mrow, tm);
            const float al = exp2f(mrow - nm);
            mrow = nm;
            lrow *= al;
#pragma unroll
            for (int j = 0; j < 4; ++j) {
                const float alr = __shfl(al, g * 4 + j);   // stats are c-indexed; oacc rows are (g*4+j)-indexed
#pragma unroll
                for (int df = 0; df < 4; ++df) oacc[df][j] *= alr;
            }
        }

        float rs = 0.0f;
#pragma unroll
        for (int half = 0; half < 2; ++half) {
            asm volatile("" ::: "memory");   // WAR fence: prior half's P reads precede these writes
#pragma unroll
            for (int mh = 0; mh < 4; ++mh) {
                const int mf = half * 4 + mh;
                const float p0 = exp2f(sacc[mf][0] - mrow);
                const float p1 = exp2f(sacc[mf][1] - mrow);
                const float p2 = exp2f(sacc[mf][2] - mrow);
                const float p3 = exp2f(sacc[mf][3] - mrow);
                rs += (p0 + p1) + (p2 + p3);
                const unsigned u0 = cvtpk(p0, p1);
                const unsigned u1 = cvtpk(p2, p3);
                const unsigned long long pw = ((unsigned long long)u1 << 32) | (unsigned long long)u0;
                *(unsigned long long*)(Pw + c * 128 + ((mh * 32 + g * 8) ^ swz)) = pw;
            }
            asm volatile("s_waitcnt lgkmcnt(0)" ::: "memory");
            __builtin_amdgcn_sched_barrier(0);
#pragma unroll
            for (int kmh = 0; kmh < 2; ++kmh) {
                const int km = half * 2 + kmh;
                const bf16x8 pa = *(const bf16x8*)(Pw + c * 128 + ((kmh * 64 + g * 16) ^ swz));
#pragma unroll
                for (int df = 0; df < 4; ++df) {
                    bf16x8 vb = *(const bf16x8*)(Vs + (df * 16 + c) * 256 + ((km * 64 + g * 16) ^ swz));
                    oacc[df] = __builtin_amdgcn_mfma_f32_16x16x32_bf16(pa, vb, oacc[df], 0, 0, 0);
                }
            }
            __builtin_amdgcn_sched_barrier(0);
        }
        rs += __shfl_xor(rs, 16);
        rs += __shfl_xor(rs, 32);
        lrow += rs;
    }

    // epilogue: oacc rows are q = s0 + g*4 + j; stats live at lane (q&15)
    const size_t obase = ((size_t)b * 2048 + s0 + g * 4) * 1024 + h * 64 + c;
#pragma unroll
    for (int j = 0; j < 4; ++j) {
        const float lr = __shfl(lrow, g * 4 + j);
        const float rinv = 1.0f / lr;
#pragma unroll
        for (int df = 0; df < 4; ++df)
            out[obase + (size_t)j * 1024 + df * 16] = f2bf(oacc[df][j] * rinv);
    }
}

// ---------- gate + residual ----------
// per row: gate = sigmoid(dot(g_silu, Wg2) + bg2); out = query + gate*retr
__global__ __launch_bounds__(256) void gate_out_k(
    const ushort* __restrict__ gs, const float* __restrict__ Wg2,
    const float* __restrict__ bg2, const float* __restrict__ query,
    const float* __restrict__ retr, float* __restrict__ out)
{
    const int r = blockIdx.x, t = threadIdx.x, w = t >> 6, l = t & 63;
    ushort4 gv = ((const ushort4*)(gs + (size_t)r * 1024))[t];
    float4 wv = ((const float4*)Wg2)[t];
    float p = bf2f(gv.x) * wv.x + bf2f(gv.y) * wv.y + bf2f(gv.z) * wv.z + bf2f(gv.w) * wv.w;
    for (int m = 1; m < 64; m <<= 1) p += __shfl_xor(p, m);
    __shared__ float red[4];
    if (l == 0) red[w] = p;
    __syncthreads();
    const float dot = red[0] + red[1] + red[2] + red[3] + bg2[0];
    const float gate = 1.0f / (1.0f + __expf(-dot));
    float4 q = ((const float4*)(query + (size_t)r * 1024))[t];
    float4 rt = ((const float4*)(retr + (size_t)r * 1024))[t];
    float4 o;
    o.x = q.x + gate * rt.x; o.y = q.y + gate * rt.y;
    o.z = q.z + gate * rt.z; o.w = q.w + gate * rt.w;
    ((float4*)(out + (size_t)r * 1024))[t] = o;
}

// ---------- launcher ----------
extern "C" void kernel_launch(void* const* d_in, const int* in_sizes, int n_in,
                              void* d_out, int out_size, void* d_ws, size_t ws_size,
                              hipStream_t stream) {
    const float* query = (const float*)d_in[0];   // 2x2048x1024
    const float* mkeys = (const float*)d_in[1];   // 2x4096x768
    const float* mvals = (const float*)d_in[2];   // 2x4096x768
    const float* Wq  = (const float*)d_in[3];
    const float* bq  = (const float*)d_in[4];
    const float* Wk  = (const float*)d_in[5];
    const float* bk  = (const float*)d_in[6];
    const float* Wv  = (const float*)d_in[7];
    const float* bv  = (const float*)d_in[8];
    const float* Wo  = (const float*)d_in[9];
    const float* bo  = (const float*)d_in[10];
    const float* Wg1 = (const float*)d_in[11];
    const float* bg1 = (const float*)d_in[12];
    const float* Wg2 = (const float*)d_in[13];
    const float* bg2 = (const float*)d_in[14];
    float* outF = (float*)d_out;

    char* ws = (char*)d_ws;
    size_t off = 0;
    auto take = [&](size_t bytes) { char* p = ws + off; off += (bytes + 255) & ~(size_t)255; return p; };
    ushort* cat    = (ushort*)take((size_t)4096 * 2048 * 2); // [query_bf | retro_bf]
    ushort* mkbf   = (ushort*)take((size_t)8192 * 768 * 2);
    ushort* mvbf   = (ushort*)take((size_t)8192 * 768 * 2);
    ushort* wqbf   = (ushort*)take((size_t)1024 * 1024 * 2);
    ushort* wkbf   = (ushort*)take((size_t)1024 * 768 * 2);
    ushort* wvbf   = (ushort*)take((size_t)1024 * 768 * 2);
    ushort* wobf   = (ushort*)take((size_t)1024 * 1024 * 2);
    ushort* wg1bf  = (ushort*)take((size_t)1024 * 2048 * 2);
    ushort* qproj  = (ushort*)take((size_t)4096 * 1024 * 2);
    ushort* kproj  = (ushort*)take((size_t)8192 * 1024 * 2);
    ushort* vprojT = (ushort*)take((size_t)1024 * 8192 * 2);
    ushort* attno  = (ushort*)take((size_t)4096 * 1024 * 2);
    float*  retro  = (float*)take((size_t)4096 * 1024 * 4);
    ushort* gsilu  = (ushort*)take((size_t)4096 * 1024 * 2);

    // conversions
    cvt_query_cat<<<4096, 256, 0, stream>>>(query, cat);
    cvt_f32_bf16<<<2048, 256, 0, stream>>>(mkeys, mkbf, 8192 * 768 / 4);
    cvt_f32_bf16<<<2048, 256, 0, stream>>>(mvals, mvbf, 8192 * 768 / 4);
    cvt_f32_bf16<<<512, 256, 0, stream>>>(Wq, wqbf, 1024 * 1024 / 4);
    cvt_f32_bf16<<<512, 256, 0, stream>>>(Wk, wkbf, 1024 * 768 / 4);
    cvt_f32_bf16<<<512, 256, 0, stream>>>(Wv, wvbf, 1024 * 768 / 4);
    cvt_f32_bf16<<<512, 256, 0, stream>>>(Wo, wobf, 1024 * 1024 / 4);
    cvt_f32_bf16<<<512, 256, 0, stream>>>(Wg1, wg1bf, 1024 * 2048 / 4);

    // Q = (query Wq^T + bq) * Dh^-0.5 * log2(e)   [base-2 softmax domain]
    const float qscale = 0.125f * 1.44269504088896340736f;
    gemm_bt<0><<<dim3(8, 32), 256, 0, stream>>>(cat, 2048, wqbf, 1024, bq, qproj, 1024, nullptr, 1024, qscale);
    // K = mk Wk^T + bk
    gemm_bt<0><<<dim3(8, 64), 256, 0, stream>>>(mkbf, 768, wkbf, 768, bk, kproj, 1024, nullptr, 768, 1.0f);
    // V^T = (mv Wv^T + bv)^T
    gemm_bt<1><<<dim3(8, 64), 256, 0, stream>>>(mvbf, 768, wvbf, 768, bv, vprojT, 8192, nullptr, 768, 1.0f);
    // attention
    attn_fwd<<<dim3(32, 16, 2), 256, 0, stream>>>(qproj, kproj, vprojT, attno);
    // retr_o = attn_out Wo^T + bo  -> f32 (residual) + bf16 into cat cols 1024..2047
    gemm_bt<2><<<dim3(8, 32), 256, 0, stream>>>(attno, 1024, wobf, 1024, bo, cat + 1024, 1024, retro, 1024, 1.0f);
    // g = silu([query; retr_o] Wg1^T + bg1)
    gemm_bt<3><<<dim3(8, 32), 256, 0, stream>>>(cat, 2048, wg1bf, 2048, bg1, gsilu, 1024, nullptr, 2048, 1.0f);
    // gate + residual
    gate_out_k<<<4096, 256, 0, stream>>>(gsilu, Wg2, bg2, query, retro, outF);
}

// Round 3
// 405.195 us; speedup vs baseline: 1.3103x; 1.1146x over previous
//
#include <hip/hip_runtime.h>

// ---------- types ----------
typedef __attribute__((ext_vector_type(8))) __bf16 bf16x8;   // MFMA A/B frag (4 VGPR)
typedef __attribute__((ext_vector_type(4))) float f32x4;     // MFMA C/D frag
typedef __attribute__((ext_vector_type(8))) unsigned short u16x8;

// fp32 -> bf16 (RNE, no NaN inputs expected)
__device__ __forceinline__ ushort f2bf(float x) {
    unsigned u = __builtin_bit_cast(unsigned, x);
    unsigned r = u + 0x7fffu + ((u >> 16) & 1u);
    return (ushort)(r >> 16);
}
__device__ __forceinline__ float bf2f(ushort u) {
    unsigned v = ((unsigned)u) << 16;
    return __builtin_bit_cast(float, v);
}

// packed f32x2 -> bf16x2 (T12)
__device__ __forceinline__ unsigned cvtpk(float lo, float hi) {
    unsigned r;
    asm("v_cvt_pk_bf16_f32 %0, %1, %2" : "=v"(r) : "v"(lo), "v"(hi));
    return r;
}

// async global->LDS, 16B per lane. LDS dest = wave-uniform base + lane*16.
__device__ __forceinline__ void gload16(const void* g, void* l) {
    __builtin_amdgcn_global_load_lds(
        (const __attribute__((address_space(1))) void*)g,
        (__attribute__((address_space(3))) void*)l,
        16, 0, 0);
}

// ---------- conversion kernels ----------
__global__ __launch_bounds__(256) void cvt_f32_bf16(const float* __restrict__ in,
                                                    ushort* __restrict__ out, int n4) {
    int i = blockIdx.x * 256 + threadIdx.x;
    int stride = gridDim.x * 256;
    for (; i < n4; i += stride) {
        float4 v = ((const float4*)in)[i];
        ushort4 o;
        o.x = f2bf(v.x); o.y = f2bf(v.y); o.z = f2bf(v.z); o.w = f2bf(v.w);
        ((ushort4*)out)[i] = o;
    }
}

// query (4096x1024 f32) -> cat buffer cols 0..1023 (row stride 2048, bf16)
__global__ __launch_bounds__(256) void cvt_query_cat(const float* __restrict__ in,
                                                     ushort* __restrict__ cat) {
    const int r = blockIdx.x, t = threadIdx.x;
    float4 v = ((const float4*)(in + (size_t)r * 1024))[t];
    ushort4 o;
    o.x = f2bf(v.x); o.y = f2bf(v.y); o.z = f2bf(v.z); o.w = f2bf(v.w);
    ((ushort4*)(cat + (size_t)r * 2048))[t] = o;
}

// ---------- GEMM: C = A(MxK,bf16) @ W(NxK,bf16)^T + bias ----------
// 128M x 64N x 64K tiles, 4 waves (2x2), wave tile 64x32, acc 4x2.
// T3-minimum prefetch: STAGE(t+1) before compute(t); 1 barrier/tile.
// EPI 0: bf16 out, (acc+bias)*scale          (ld0 = N)
// EPI 1: bf16 out TRANSPOSED out[col*ld0+row] (ld0 = Mrows)
// EPI 2: f32 out (ld0) + bf16 out into o_bf with row stride 2048
// EPI 3: silu(acc+bias) -> bf16 out (ld0)
template<int EPI>
__global__ __launch_bounds__(256) void gemm_bt(
    const ushort* __restrict__ A, int lda,
    const ushort* __restrict__ Bw, int ldb,
    const float* __restrict__ bias,
    ushort* __restrict__ o_bf, int ld0,
    float* __restrict__ o_f32,
    int K, float scale)
{
    __shared__ __align__(1024) char smem[49152];  // As 2x16K @0, Bs 2x8K @32768
    char* As = smem;
    char* Bs = smem + 32768;
    const int t = threadIdx.x, w = t >> 6, l = t & 63, g = l >> 4, c = l & 15;
    const int wr = w >> 1, wc = w & 1;
    const long m0 = (long)blockIdx.y * 128, n0 = (long)blockIdx.x * 64;
    const size_t ldaB = (size_t)lda * 2, ldbB = (size_t)ldb * 2;
    const int swz = (c & 7) << 4;

    f32x4 acc[4][2];
#pragma unroll
    for (int i = 0; i < 4; ++i)
#pragma unroll
        for (int j = 0; j < 2; ++j) acc[i][j] = (f32x4)0.0f;

    auto stage = [&](int kt, int bufsel) {
        const char* Ab = (const char*)A + (size_t)kt * 128;
        const char* Bb = (const char*)Bw + (size_t)kt * 128;
#pragma unroll
        for (int i = 0; i < 4; ++i) {
            int o = (i * 4 + w) * 1024 + l * 16;
            int row = o >> 7, cb = o & 127;
            gload16(Ab + (size_t)(m0 + row) * ldaB + (cb ^ ((row & 7) << 4)),
                    As + bufsel * 16384 + (i * 4 + w) * 1024);
        }
#pragma unroll
        for (int i = 0; i < 2; ++i) {
            int o = (i * 4 + w) * 1024 + l * 16;
            int row = o >> 7, cb = o & 127;
            gload16(Bb + (size_t)(n0 + row) * ldbB + (cb ^ ((row & 7) << 4)),
                    Bs + bufsel * 8192 + (i * 4 + w) * 1024);
        }
    };

    const int nkt = K >> 6;
    stage(0, 0);
    __syncthreads();   // drains vmcnt(0)

    for (int kt = 0; kt < nkt; ++kt) {
        const int cur = kt & 1;
        if (kt + 1 < nkt) stage(kt + 1, cur ^ 1);   // prefetch overlaps compute
        const char* Ac = As + cur * 16384;
        const char* Bc = Bs + cur * 8192;
        bf16x8 af[2][4], bfr[2][2];
#pragma unroll
        for (int kf = 0; kf < 2; ++kf) {
            int cbk = (kf * 64 + g * 16) ^ swz;
#pragma unroll
            for (int i = 0; i < 4; ++i)
                af[kf][i] = *(const bf16x8*)(Ac + (wr * 64 + i * 16 + c) * 128 + cbk);
#pragma unroll
            for (int j = 0; j < 2; ++j)
                bfr[kf][j] = *(const bf16x8*)(Bc + (wc * 32 + j * 16 + c) * 128 + cbk);
        }
#pragma unroll
        for (int kf = 0; kf < 2; ++kf)
#pragma unroll
            for (int i = 0; i < 4; ++i)
#pragma unroll
                for (int j = 0; j < 2; ++j)
                    acc[i][j] = __builtin_amdgcn_mfma_f32_16x16x32_bf16(
                        af[kf][i], bfr[kf][j], acc[i][j], 0, 0, 0);
        __syncthreads();   // drain prefetch vmcnt + WAR protection
    }

    // epilogue: C/D layout col = l&15, row = (l>>4)*4 + jj  [verified m89/m91]
#pragma unroll
    for (int i = 0; i < 4; ++i)
#pragma unroll
        for (int j = 0; j < 2; ++j) {
            const long col = n0 + wc * 32 + j * 16 + c;
            const float bs = bias[col];
            const long rowb = m0 + wr * 64 + i * 16 + g * 4;
            if (EPI == 1) {
                ushort4 o;
                o.x = f2bf(acc[i][j][0] + bs);
                o.y = f2bf(acc[i][j][1] + bs);
                o.z = f2bf(acc[i][j][2] + bs);
                o.w = f2bf(acc[i][j][3] + bs);
                *(ushort4*)(o_bf + col * (long)ld0 + rowb) = o;
            } else {
#pragma unroll
                for (int jj = 0; jj < 4; ++jj) {
                    const long row = rowb + jj;
                    const float v = acc[i][j][jj] + bs;
                    if (EPI == 0) {
                        o_bf[row * (long)ld0 + col] = f2bf(v * scale);
                    } else if (EPI == 2) {
                        o_f32[row * (long)ld0 + col] = v;
                        o_bf[row * 2048 + col] = f2bf(v);
                    } else { // EPI == 3 : silu
                        const float sv = v / (1.0f + __expf(-v));
                        o_bf[row * (long)ld0 + col] = f2bf(sv);
                    }
                }
            }
        }
}

// ---------- flash attention (swapped-QK^T, dbuf prefetch, MFMA row-sum) ----------
// grid (S/64, H, B), 256 threads = 4 waves; wave owns 16 q-rows; KVBLK=64.
// qp: (B*S)x1024 bf16 PRE-SCALED by Dh^-0.5*log2(e); kp: (B*M)x1024 bf16;
// vT: 1024x(B*M) bf16 (transposed V projection); out: (B*S)x1024 bf16.
// Lane (c,g) owns P[q=s0+c][k=mf*16+g*4+j]; softmax denominator accumulated
// by an extra MFMA against an all-ones B-fragment (lane-local in C layout).
__global__ __launch_bounds__(256, 4) void attn_fwd(
    const ushort* __restrict__ qp, const ushort* __restrict__ kp,
    const ushort* __restrict__ vT, ushort* __restrict__ out)
{
    __shared__ __align__(1024) char smem[40960];
    // Ks: 2 x 8KB @ 0; Vs: 2 x 8KB @ 16384; Ps: 4 x 2KB @ 32768
    const int t = threadIdx.x, w = t >> 6, l = t & 63, g = l >> 4, c = l & 15;
    const int b = blockIdx.z, h = blockIdx.y;
    const int s0 = blockIdx.x * 64 + w * 16;
    const int swz = (c & 7) << 4;

    // Q frag: row = s0+c, k = kf*32 + g*8 .. +7
    const size_t qbase = ((size_t)b * 2048 + s0 + c) * 1024 + h * 64 + g * 8;
    const bf16x8 qf0 = *(const bf16x8*)(qp + qbase);
    const bf16x8 qf1 = *(const bf16x8*)(qp + qbase + 32);

    const u16x8 ones_u = (u16x8)(ushort)0x3F80;           // bf16 1.0 x8
    const bf16x8 ones = __builtin_bit_cast(bf16x8, ones_u);

    f32x4 oacc[4];
    f32x4 lacc = (f32x4)0.0f;     // softmax denom, lane-local per q-row g*4+j
#pragma unroll
    for (int d = 0; d < 4; ++d) oacc[d] = (f32x4)0.0f;
    float mrow = -1e30f;          // running max for q-row s0+c (dup over g)

    const char* kpB = (const char*)kp + (size_t)b * 4096 * 2048 + h * 128;
    const char* vTB = (const char*)vT + (size_t)h * 64 * 16384 + (size_t)b * 4096 * 2;
    char* Pw = smem + 32768 + w * 2048;

    auto stage = [&](int mt, int bufsel) {
#pragma unroll
        for (int i = 0; i < 2; ++i) {
            int o = (i * 4 + w) * 1024 + l * 16;
            int row = o >> 7, cb = o & 127;
            gload16(kpB + (size_t)(mt + row) * 2048 + (cb ^ ((row & 7) << 4)),
                    smem + bufsel * 8192 + (i * 4 + w) * 1024);
            gload16(vTB + (size_t)row * 16384 + (size_t)mt * 2 + (cb ^ ((row & 7) << 4)),
                    smem + 16384 + bufsel * 8192 + (i * 4 + w) * 1024);
        }
    };

    stage(0, 0);
    __syncthreads();

    for (int ti = 0; ti < 64; ++ti) {
        const int cur = ti & 1;
        if (ti < 63) stage((ti + 1) << 6, cur ^ 1);     // prefetch next K/V tile
        const char* Ksc = smem + cur * 8192;
        const char* Vsc = smem + 16384 + cur * 8192;

        // S^T = K Q^T : lane (c,g) gets S[q=s0+c][k = mf*16+g*4+j]
        f32x4 sacc[4];
#pragma unroll
        for (int mf = 0; mf < 4; ++mf) sacc[mf] = (f32x4)0.0f;
#pragma unroll
        for (int kf = 0; kf < 2; ++kf) {
            const int cbk = (kf * 64 + g * 16) ^ swz;
            const bf16x8 q = kf ? qf1 : qf0;
#pragma unroll
            for (int mf = 0; mf < 4; ++mf) {
                bf16x8 kb = *(const bf16x8*)(Ksc + (mf * 16 + c) * 128 + cbk);
                sacc[mf] = __builtin_amdgcn_mfma_f32_16x16x32_bf16(kb, q, sacc[mf], 0, 0, 0);
            }
        }

        // lane-local max over 16 values (max3-friendly nesting) + 2 shfl rounds
        float tm;
        {
            float a0 = fmaxf(fmaxf(sacc[0][0], sacc[0][1]), fmaxf(sacc[0][2], sacc[0][3]));
            float a1 = fmaxf(fmaxf(sacc[1][0], sacc[1][1]), fmaxf(sacc[1][2], sacc[1][3]));
            float a2 = fmaxf(fmaxf(sacc[2][0], sacc[2][1]), fmaxf(sacc[2][2], sacc[2][3]));
            float a3 = fmaxf(fmaxf(sacc[3][0], sacc[3][1]), fmaxf(sacc[3][2], sacc[3][3]));
            tm = fmaxf(fmaxf(a0, a1), fmaxf(a2, a3));
        }
        tm = fmaxf(tm, __shfl_xor(tm, 16));
        tm = fmaxf(tm, __shfl_xor(tm, 32));

        // T13 defer-max: rescale only when tile max outgrows running max by >8
        if (!__all(tm <= mrow + 8.0f)) {
            const float nm = fmaxf(mrow, tm);
            const float al = exp2f(mrow - nm);
            mrow = nm;
#pragma unroll
            for (int j = 0; j < 4; ++j) {
                const float alr = __shfl(al, g * 4 + j);   // stats c-indexed; acc rows (g*4+j)-indexed
                lacc[j] *= alr;
#pragma unroll
                for (int df = 0; df < 4; ++df) oacc[df][j] *= alr;
            }
        }

        // exp + pack all of P (16 vals -> 4 ds_write_b64), then PV + denom MFMA
        asm volatile("" ::: "memory");   // keep prior-tile P reads before these writes
#pragma unroll
        for (int mf = 0; mf < 4; ++mf) {
            const float p0 = exp2f(sacc[mf][0] - mrow);
            const float p1 = exp2f(sacc[mf][1] - mrow);
            const float p2 = exp2f(sacc[mf][2] - mrow);
            const float p3 = exp2f(sacc[mf][3] - mrow);
            const unsigned u0 = cvtpk(p0, p1);
            const unsigned u1 = cvtpk(p2, p3);
            const unsigned long long pw = ((unsigned long long)u1 << 32) | (unsigned long long)u0;
            *(unsigned long long*)(Pw + c * 128 + ((mf * 32 + g * 8) ^ swz)) = pw;
        }
        asm volatile("s_waitcnt lgkmcnt(0)" ::: "memory");
        __builtin_amdgcn_sched_barrier(0);
#pragma unroll
        for (int km = 0; km < 2; ++km) {
            const int cbm = (km * 64 + g * 16) ^ swz;
            const bf16x8 pa = *(const bf16x8*)(Pw + c * 128 + cbm);
            lacc = __builtin_amdgcn_mfma_f32_16x16x32_bf16(pa, ones, lacc, 0, 0, 0);
#pragma unroll
            for (int df = 0; df < 4; ++df) {
                bf16x8 vb = *(const bf16x8*)(Vsc + (df * 16 + c) * 128 + cbm);
                oacc[df] = __builtin_amdgcn_mfma_f32_16x16x32_bf16(pa, vb, oacc[df], 0, 0, 0);
            }
        }
        __builtin_amdgcn_sched_barrier(0);
        __syncthreads();   // drain prefetch + WAR for next stage
    }

    // epilogue: oacc rows are q = s0 + g*4 + j; lacc[j] is that row's denom (lane-local)
    const size_t obase = ((size_t)b * 2048 + s0 + g * 4) * 1024 + h * 64 + c;
#pragma unroll
    for (int j = 0; j < 4; ++j) {
        const float rinv = 1.0f / lacc[j];
#pragma unroll
        for (int df = 0; df < 4; ++df)
            out[obase + (size_t)j * 1024 + df * 16] = f2bf(oacc[df][j] * rinv);
    }
}

// ---------- gate + residual ----------
// per row: gate = sigmoid(dot(g_silu, Wg2) + bg2); out = query + gate*retr
__global__ __launch_bounds__(256) void gate_out_k(
    const ushort* __restrict__ gs, const float* __restrict__ Wg2,
    const float* __restrict__ bg2, const float* __restrict__ query,
    const float* __restrict__ retr, float* __restrict__ out)
{
    const int r = blockIdx.x, t = threadIdx.x, w = t >> 6, l = t & 63;
    ushort4 gv = ((const ushort4*)(gs + (size_t)r * 1024))[t];
    float4 wv = ((const float4*)Wg2)[t];
    float p = bf2f(gv.x) * wv.x + bf2f(gv.y) * wv.y + bf2f(gv.z) * wv.z + bf2f(gv.w) * wv.w;
    for (int m = 1; m < 64; m <<= 1) p += __shfl_xor(p, m);
    __shared__ float red[4];
    if (l == 0) red[w] = p;
    __syncthreads();
    const float dot = red[0] + red[1] + red[2] + red[3] + bg2[0];
    const float gate = 1.0f / (1.0f + __expf(-dot));
    float4 q = ((const float4*)(query + (size_t)r * 1024))[t];
    float4 rt = ((const float4*)(retr + (size_t)r * 1024))[t];
    float4 o;
    o.x = q.x + gate * rt.x; o.y = q.y + gate * rt.y;
    o.z = q.z + gate * rt.z; o.w = q.w + gate * rt.w;
    ((float4*)(out + (size_t)r * 1024))[t] = o;
}

// ---------- launcher ----------
extern "C" void kernel_launch(void* const* d_in, const int* in_sizes, int n_in,
                              void* d_out, int out_size, void* d_ws, size_t ws_size,
                              hipStream_t stream) {
    const float* query = (const float*)d_in[0];   // 2x2048x1024
    const float* mkeys = (const float*)d_in[1];   // 2x4096x768
    const float* mvals = (const float*)d_in[2];   // 2x4096x768
    const float* Wq  = (const float*)d_in[3];
    const float* bq  = (const float*)d_in[4];
    const float* Wk  = (const float*)d_in[5];
    const float* bk  = (const float*)d_in[6];
    const float* Wv  = (const float*)d_in[7];
    const float* bv  = (const float*)d_in[8];
    const float* Wo  = (const float*)d_in[9];
    const float* bo  = (const float*)d_in[10];
    const float* Wg1 = (const float*)d_in[11];
    const float* bg1 = (const float*)d_in[12];
    const float* Wg2 = (const float*)d_in[13];
    const float* bg2 = (const float*)d_in[14];
    float* outF = (float*)d_out;

    char* ws = (char*)d_ws;
    size_t off = 0;
    auto take = [&](size_t bytes) { char* p = ws + off; off += (bytes + 255) & ~(size_t)255; return p; };
    ushort* cat    = (ushort*)take((size_t)4096 * 2048 * 2); // [query_bf | retro_bf]
    ushort* mkbf   = (ushort*)take((size_t)8192 * 768 * 2);
    ushort* mvbf   = (ushort*)take((size_t)8192 * 768 * 2);
    ushort* wqbf   = (ushort*)take((size_t)1024 * 1024 * 2);
    ushort* wkbf   = (ushort*)take((size_t)1024 * 768 * 2);
    ushort* wvbf   = (ushort*)take((size_t)1024 * 768 * 2);
    ushort* wobf   = (ushort*)take((size_t)1024 * 1024 * 2);
    ushort* wg1bf  = (ushort*)take((size_t)1024 * 2048 * 2);
    ushort* qproj  = (ushort*)take((size_t)4096 * 1024 * 2);
    ushort* kproj  = (ushort*)take((size_t)8192 * 1024 * 2);
    ushort* vprojT = (ushort*)take((size_t)1024 * 8192 * 2);
    ushort* attno  = (ushort*)take((size_t)4096 * 1024 * 2);
    float*  retro  = (float*)take((size_t)4096 * 1024 * 4);
    ushort* gsilu  = (ushort*)take((size_t)4096 * 1024 * 2);

    // conversions
    cvt_query_cat<<<4096, 256, 0, stream>>>(query, cat);
    cvt_f32_bf16<<<2048, 256, 0, stream>>>(mkeys, mkbf, 8192 * 768 / 4);
    cvt_f32_bf16<<<2048, 256, 0, stream>>>(mvals, mvbf, 8192 * 768 / 4);
    cvt_f32_bf16<<<512, 256, 0, stream>>>(Wq, wqbf, 1024 * 1024 / 4);
    cvt_f32_bf16<<<512, 256, 0, stream>>>(Wk, wkbf, 1024 * 768 / 4);
    cvt_f32_bf16<<<512, 256, 0, stream>>>(Wv, wvbf, 1024 * 768 / 4);
    cvt_f32_bf16<<<512, 256, 0, stream>>>(Wo, wobf, 1024 * 1024 / 4);
    cvt_f32_bf16<<<512, 256, 0, stream>>>(Wg1, wg1bf, 1024 * 2048 / 4);

    // Q = (query Wq^T + bq) * Dh^-0.5 * log2(e)   [base-2 softmax domain]
    const float qscale = 0.125f * 1.44269504088896340736f;
    gemm_bt<0><<<dim3(16, 32), 256, 0, stream>>>(cat, 2048, wqbf, 1024, bq, qproj, 1024, nullptr, 1024, qscale);
    // K = mk Wk^T + bk
    gemm_bt<0><<<dim3(16, 64), 256, 0, stream>>>(mkbf, 768, wkbf, 768, bk, kproj, 1024, nullptr, 768, 1.0f);
    // V^T = (mv Wv^T + bv)^T
    gemm_bt<1><<<dim3(16, 64), 256, 0, stream>>>(mvbf, 768, wvbf, 768, bv, vprojT, 8192, nullptr, 768, 1.0f);
    // attention
    attn_fwd<<<dim3(32, 16, 2), 256, 0, stream>>>(qproj, kproj, vprojT, attno);
    // retr_o = attn_out Wo^T + bo  -> f32 (residual) + bf16 into cat cols 1024..2047
    gemm_bt<2><<<dim3(16, 32), 256, 0, stream>>>(attno, 1024, wobf, 1024, bo, cat + 1024, 1024, retro, 1024, 1.0f);
    // g = silu([query; retr_o] Wg1^T + bg1)
    gemm_bt<3><<<dim3(16, 32), 256, 0, stream>>>(cat, 2048, wg1bf, 2048, bg1, gsilu, 1024, nullptr, 2048, 1.0f);
    // gate + residual
    gate_out_k<<<4096, 256, 0, stream>>>(gsilu, Wg2, bg2, query, retro, outF);
}